// Round 19
// baseline (159.699 us; speedup 1.0000x reference)
//
#include <hip/hip_runtime.h>
#include <hip/hip_bf16.h>
#include <math.h>

#define IN_DIM 128
#define OUT_DIM 128
#define NHEAD 4
#define HC 32
#define NEG_SLOPE 0.2f
#define LN_EPS 1e-5f
#define SM_EPS 1e-16f

#define NB_SHIFT 9
#define BDST 512            // 1 << NB_SHIFT
#define NBUCK_MAX 256
#define BIN_ITER 28
#define BIN_CHUNK (BIN_ITER * 256)
#define SRC_BITS 17         // N < 131072
#define SRC_MASK ((1u << SRC_BITS) - 1u)
#define BCAP_SHIFT 14
#define BCAP (1 << BCAP_SHIFT)

typedef __attribute__((ext_vector_type(8))) short bf16x8;
typedef __attribute__((ext_vector_type(4))) short short4v;
typedef __attribute__((ext_vector_type(4))) float f32x4;

__device__ __forceinline__ float leaky(float v) { return v > 0.f ? v : NEG_SLOPE * v; }

__device__ __forceinline__ short f2b(float f) {
    __hip_bfloat16 b = __float2bfloat16(f);
    return *reinterpret_cast<short*>(&b);
}
__device__ __forceinline__ float b2f(short s) {
    return __uint_as_float(((unsigned)(unsigned short)s) << 16);
}

// byte offset into a tile of 256-byte rows, XOR row-swizzled (G4 fix)
__device__ __forceinline__ int swz(int row, int byteInRow) {
    return row * 256 + (byteInRow ^ ((row & 7) << 4));
}

// ---------------- K1: fused { edge binning (2-pass, no reg arrays) | prepW } ----------------
__global__ void __launch_bounds__(256)
k_bin_prep(const int* __restrict__ ei, int* __restrict__ bcur, unsigned* __restrict__ binned,
           const float* __restrict__ W, __hip_bfloat16* __restrict__ WtB,
           int E, int N, int nblk_bin)
{
    __shared__ int cnt[NBUCK_MAX];
    __shared__ int gb[NBUCK_MAX];
    __shared__ int cnt2[NBUCK_MAX];
    const int t = threadIdx.x;

    if ((int)blockIdx.x < nblk_bin) {
        int tot = E + N;
        int base = (int)blockIdx.x * BIN_CHUNK;

        cnt[t] = 0;
        __syncthreads();
        // pass A: count dst buckets
        #pragma unroll 4
        for (int k = 0; k < BIN_ITER; ++k) {
            int e = base + k * 256 + t;
            if (e < tot) {
                int d = (e < E) ? ei[E + e] : (e - E);
                atomicAdd(&cnt[d >> NB_SHIFT], 1);
            }
        }
        __syncthreads();
        gb[t] = cnt[t] ? ((t << BCAP_SHIFT) + atomicAdd(&bcur[t], cnt[t])) : 0;
        cnt2[t] = 0;
        __syncthreads();
        // pass B: re-read, rank via fresh cursor, write packed
        #pragma unroll 4
        for (int k = 0; k < BIN_ITER; ++k) {
            int e = base + k * 256 + t;
            if (e < tot) {
                int d = (e < E) ? ei[E + e] : (e - E);
                int b = d >> NB_SHIFT;
                int r = atomicAdd(&cnt2[b], 1);
                int s = (e < E) ? ei[e] : (e - E);
                binned[gb[b] + r] = (unsigned)s | ((unsigned)(d & (BDST - 1)) << SRC_BITS);
            }
        }
    } else {
        // prepW: W[k][j] fp32 -> WtB[j][k] bf16 (64 blocks cover 16384 elems)
        int t0 = ((int)blockIdx.x - nblk_bin) * 256 + t;
        int k = t0 >> 7, j = t0 & 127;
        WtB[j * IN_DIM + k] = __float2bfloat16(W[t0]);
    }
}

// ---------------- K2: fused { per-bucket CSR (first) | MFMA GEMM + alpha } ----------------
__global__ void __launch_bounds__(256)
k_csr_gemm(const unsigned* __restrict__ binned, const int* __restrict__ bcur,
           int* __restrict__ rowbeg, int* __restrict__ rowend, int* __restrict__ csr_src,
           const float* __restrict__ x, const __hip_bfloat16* __restrict__ WtB,
           const float* __restrict__ a_src, const float* __restrict__ a_dst,
           __hip_bfloat16* __restrict__ hB, float* __restrict__ asrc_out,
           float* __restrict__ adst_out,
           int N, int nbuck)
{
    __shared__ __align__(16) char lds[32768];
    const int t = threadIdx.x;

    if ((int)blockIdx.x < nbuck) {
        // ================= bucket CSR branch =================
        int* cnt = (int*)lds;              // [BDST]
        int* s2  = (int*)(lds + BDST * 4); // [256]
        int b = blockIdx.x;
        int d0 = b << NB_SHIFT;
        int base = b << BCAP_SHIFT;
        int ne = bcur[b];

        cnt[t] = 0; cnt[t + 256] = 0;
        __syncthreads();
        for (int i = t; i < ne; i += 256) {
            unsigned p = binned[base + i];
            atomicAdd(&cnt[p >> SRC_BITS], 1);
        }
        __syncthreads();
        int c0 = cnt[2 * t], c1 = cnt[2 * t + 1];
        s2[t] = c0 + c1;
        __syncthreads();
        #pragma unroll
        for (int off = 1; off < 256; off <<= 1) {
            int tmp = (t >= off) ? s2[t - off] : 0;
            __syncthreads();
            s2[t] += tmp;
            __syncthreads();
        }
        int e0 = (t ? s2[t - 1] : 0);
        cnt[2 * t] = e0;
        cnt[2 * t + 1] = e0 + c0;
        if (d0 + 2 * t < N) {
            rowbeg[d0 + 2 * t] = base + e0;
            rowend[d0 + 2 * t] = base + e0 + c0;
        }
        if (d0 + 2 * t + 1 < N) {
            rowbeg[d0 + 2 * t + 1] = base + e0 + c0;
            rowend[d0 + 2 * t + 1] = base + e0 + c0 + c1;
        }
        __syncthreads();
        for (int i = t; i < ne; i += 256) {
            unsigned p = binned[base + i];
            int r = atomicAdd(&cnt[p >> SRC_BITS], 1);
            csr_src[base + r] = (int)(p & SRC_MASK);
        }
    } else {
        // ================= GEMM + alpha branch =================
        const int node0 = ((int)blockIdx.x - nbuck) * 64;

        // stage Wt: bf16 [col][k] swizzled rows, 32KB
        #pragma unroll
        for (int i = 0; i < 16; ++i) {
            int idx = (i * 256 + t) * 4;
            int col = idx >> 7, k = idx & 127;
            short4v w4 = *reinterpret_cast<const short4v*>((const short*)WtB + idx);
            *reinterpret_cast<short4v*>(lds + swz(col, 2 * k)) = w4;
        }

        const int wave = t >> 6, l = t & 63;
        const int lr = l & 15, lg = l >> 4;

        // A-fragments direct from x
        int arow = node0 + wave * 16 + lr;
        bf16x8 afrag[4];
        if (arow < N) {
            const float* xr = x + (size_t)arow * IN_DIM + lg * 8;
            #pragma unroll
            for (int kk = 0; kk < 4; ++kk) {
                float4 xa = *reinterpret_cast<const float4*>(xr + kk * 32);
                float4 xc = *reinterpret_cast<const float4*>(xr + kk * 32 + 4);
                afrag[kk] = (bf16x8){ f2b(xa.x), f2b(xa.y), f2b(xa.z), f2b(xa.w),
                                      f2b(xc.x), f2b(xc.y), f2b(xc.z), f2b(xc.w) };
            }
        } else {
            #pragma unroll
            for (int kk = 0; kk < 4; ++kk)
                afrag[kk] = (bf16x8){0,0,0,0,0,0,0,0};
        }

        __syncthreads();   // Wt staged

        f32x4 acc[8];
        #pragma unroll
        for (int cg = 0; cg < 8; ++cg) acc[cg] = (f32x4){0.f, 0.f, 0.f, 0.f};

        #pragma unroll
        for (int cg = 0; cg < 8; ++cg) {
            #pragma unroll
            for (int kk = 0; kk < 4; ++kk) {
                bf16x8 b = *reinterpret_cast<bf16x8*>(lds + swz(cg * 16 + lr, kk * 64 + lg * 16));
                acc[cg] = __builtin_amdgcn_mfma_f32_16x16x32_bf16(afrag[kk], b, acc[cg], 0, 0, 0);
            }
        }

        // repack D-fragments into bf16 out-tile in LDS (Wt dead now)
        __syncthreads();
        #pragma unroll
        for (int q = 0; q < 4; ++q) {
            int row = wave * 16 + lg * 4 + q;
            #pragma unroll
            for (int cg = 0; cg < 8; ++cg)
                *reinterpret_cast<short*>(lds + swz(row, (cg * 16 + lr) * 2)) = f2b(acc[cg][q]);
        }
        __syncthreads();

        // wide coalesced store + fused alpha: thread t -> row t>>2, head t&3
        {
            int row = t >> 2;
            int node = node0 + row;
            int head = t & 3;
            if (node < N) {
                char* dst = (char*)(hB + (size_t)node * OUT_DIM);
                const float4* asv = (const float4*)(a_src + head * HC);
                const float4* adv = (const float4*)(a_dst + head * HC);
                float s = 0.f, dd = 0.f;
                #pragma unroll
                for (int c = 0; c < 4; ++c) {
                    int bir = head * 64 + c * 16;
                    bf16x8 vv = *reinterpret_cast<bf16x8*>(lds + swz(row, bir));
                    *reinterpret_cast<bf16x8*>(dst + bir) = vv;
                    float4 a0 = asv[c * 2], a1 = asv[c * 2 + 1];
                    float4 d0 = adv[c * 2], d1 = adv[c * 2 + 1];
                    s  = fmaf(b2f(vv[0]), a0.x, s);  dd = fmaf(b2f(vv[0]), d0.x, dd);
                    s  = fmaf(b2f(vv[1]), a0.y, s);  dd = fmaf(b2f(vv[1]), d0.y, dd);
                    s  = fmaf(b2f(vv[2]), a0.z, s);  dd = fmaf(b2f(vv[2]), d0.z, dd);
                    s  = fmaf(b2f(vv[3]), a0.w, s);  dd = fmaf(b2f(vv[3]), d0.w, dd);
                    s  = fmaf(b2f(vv[4]), a1.x, s);  dd = fmaf(b2f(vv[4]), d1.x, dd);
                    s  = fmaf(b2f(vv[5]), a1.y, s);  dd = fmaf(b2f(vv[5]), d1.y, dd);
                    s  = fmaf(b2f(vv[6]), a1.z, s);  dd = fmaf(b2f(vv[6]), d1.z, dd);
                    s  = fmaf(b2f(vv[7]), a1.w, s);  dd = fmaf(b2f(vv[7]), d1.w, dd);
                }
                asrc_out[node * NHEAD + head] = s;
                adst_out[node * NHEAD + head] = dd;
            }
        }
    }
}

// ---------------- K4: gather + softmax + aggregate + bias + LN + ReLU ----------------
// Exact R14 structure (best measured: 78.8 us).
__global__ void k_gather(const int* __restrict__ csr_src,
                         const int* __restrict__ rowbeg, const int* __restrict__ rowend,
                         const __hip_bfloat16* __restrict__ hB,
                         const float* __restrict__ asrc, const float* __restrict__ adst,
                         const float* __restrict__ bias, const float* __restrict__ gamma,
                         const float* __restrict__ beta, float* __restrict__ out, int N)
{
    int wave = threadIdx.x >> 6;
    int l = threadIdx.x & 63;
    int d = blockIdx.x * 4 + wave;
    if (d >= N) return;
    int head = l >> 4;
    const char* hp = (const char*)hB;
    unsigned voff = (unsigned)(l << 2);
    float ad = adst[d * NHEAD + head];
    int beg = __builtin_amdgcn_readfirstlane(rowbeg[d]);
    int end = __builtin_amdgcn_readfirstlane(rowend[d]);

    float ax0 = 0.f, ay0 = 0.f, dn0 = 0.f;
    float ax1 = 0.f, ay1 = 0.f, dn1 = 0.f;

    int idx = beg + (l & 15);
    int cl = idx < end ? idx : end - 1;
    int smine = csr_src[cl];
    float v = (idx < end) ? asrc[(unsigned)smine * NHEAD + head] : -1e30f;

    for (int c = beg; c < end; c += 16) {
        float ee = __expf(leaky(v + ad));        // padding -> exp(-2e29) = 0
        int scur = smine;
        int c2 = c + 16;
        if (c2 < end) {
            int idx2 = c2 + (l & 15);
            int cl2 = idx2 < end ? idx2 : end - 1;
            smine = csr_src[cl2];
            v = (idx2 < end) ? asrc[(unsigned)smine * NHEAD + head] : -1e30f;
        }

#define GLOAD(E_)                                                                     \
        unsigned se##E_ = (unsigned)__builtin_amdgcn_readlane(scur, (E_));            \
        unsigned hv##E_ = *(const unsigned*)(hp + ((se##E_ << 8) + voff));
#define GCONS(E_, AX_, AY_, DN_) {                                                    \
        float eb = __int_as_float(__builtin_amdgcn_ds_swizzle(                        \
            __float_as_int(ee), 0x10 | ((E_) << 5)));                                 \
        AX_ = fmaf(eb, __uint_as_float(hv##E_ << 16), AX_);                           \
        AY_ = fmaf(eb, __uint_as_float(hv##E_ & 0xffff0000u), AY_);  DN_ += eb;       \
    }
        { GLOAD(0) GLOAD(1) GLOAD(2) GLOAD(3) GLOAD(4) GLOAD(5) GLOAD(6) GLOAD(7)
          GCONS(0, ax0, ay0, dn0) GCONS(1, ax1, ay1, dn1)
          GCONS(2, ax0, ay0, dn0) GCONS(3, ax1, ay1, dn1)
          GCONS(4, ax0, ay0, dn0) GCONS(5, ax1, ay1, dn1)
          GCONS(6, ax0, ay0, dn0) GCONS(7, ax1, ay1, dn1) }
        { GLOAD(8) GLOAD(9) GLOAD(10) GLOAD(11) GLOAD(12) GLOAD(13) GLOAD(14) GLOAD(15)
          GCONS(8, ax0, ay0, dn0)  GCONS(9, ax1, ay1, dn1)
          GCONS(10, ax0, ay0, dn0) GCONS(11, ax1, ay1, dn1)
          GCONS(12, ax0, ay0, dn0) GCONS(13, ax1, ay1, dn1)
          GCONS(14, ax0, ay0, dn0) GCONS(15, ax1, ay1, dn1) }
#undef GLOAD
#undef GCONS
    }

    float accx = ax0 + ax1, accy = ay0 + ay1, den = dn0 + dn1;
    float inv = 1.f / (den + SM_EPS);
    float vx = accx * inv + bias[2 * l];
    float vy = accy * inv + bias[2 * l + 1];

    float s1 = vx + vy;
    float s2 = vx * vx + vy * vy;
    #pragma unroll
    for (int m = 32; m >= 1; m >>= 1) {
        s1 += __shfl_xor(s1, m, 64);
        s2 += __shfl_xor(s2, m, 64);
    }
    float mean = s1 * (1.f / OUT_DIM);
    float var = s2 * (1.f / OUT_DIM) - mean * mean;
    float r = rsqrtf(var + LN_EPS);
    float ox = (vx - mean) * r * gamma[2 * l] + beta[2 * l];
    float oy = (vy - mean) * r * gamma[2 * l + 1] + beta[2 * l + 1];
    ox = ox > 0.f ? ox : 0.f;
    oy = oy > 0.f ? oy : 0.f;
    *reinterpret_cast<float2*>(&out[(size_t)d * OUT_DIM + 2 * l]) = make_float2(ox, oy);
}

extern "C" void kernel_launch(void* const* d_in, const int* in_sizes, int n_in,
                              void* d_out, int out_size, void* d_ws, size_t ws_size,
                              hipStream_t stream) {
    const float* x      = (const float*)d_in[0];
    const int*   ei     = (const int*)d_in[1];
    const float* W      = (const float*)d_in[2];
    const float* a_src  = (const float*)d_in[3];
    const float* a_dst  = (const float*)d_in[4];
    const float* bias   = (const float*)d_in[5];
    const float* gamma  = (const float*)d_in[6];
    const float* beta   = (const float*)d_in[7];
    float* out = (float*)d_out;

    const int N = in_sizes[0] / IN_DIM;
    const int E = in_sizes[1] / 2;
    const int TOT = E + N;
    const int nbuck = (N + BDST - 1) >> NB_SHIFT;
    const int nblk_gemm = (N + 63) / 64;
    const int nblk_bin = (TOT + BIN_CHUNK - 1) / BIN_CHUNK;

    // workspace layout
    char* p = (char*)d_ws;
    __hip_bfloat16* hB = (__hip_bfloat16*)p;  p += (size_t)N * OUT_DIM * sizeof(__hip_bfloat16);
    __hip_bfloat16* WtB = (__hip_bfloat16*)p; p += (size_t)IN_DIM * OUT_DIM * sizeof(__hip_bfloat16);
    float* asrc   = (float*)p;                p += (size_t)N * NHEAD * sizeof(float);
    float* adst   = (float*)p;                p += (size_t)N * NHEAD * sizeof(float);
    int* bcur     = (int*)p;                  p += NBUCK_MAX * sizeof(int);
    int* rowbeg   = (int*)p;                  p += (size_t)N * sizeof(int);
    int* rowend   = (int*)p;                  p += (size_t)N * sizeof(int);
    unsigned* binned = (unsigned*)p;          p += (size_t)nbuck * BCAP * sizeof(unsigned);
    int* csr_src  = (int*)p;                  p += (size_t)nbuck * BCAP * sizeof(int);

    (void)hipMemsetAsync(bcur, 0, NBUCK_MAX * sizeof(int), stream);

    k_bin_prep<<<nblk_bin + 64, 256, 0, stream>>>(ei, bcur, binned, W, WtB, E, N, nblk_bin);
    k_csr_gemm<<<nbuck + nblk_gemm, 256, 0, stream>>>(binned, bcur, rowbeg, rowend, csr_src,
                                                      x, WtB, a_src, a_dst, hB, asrc, adst,
                                                      N, nbuck);
    k_gather<<<(N + 3) / 4, 256, 0, stream>>>(csr_src, rowbeg, rowend, hB, asrc, adst,
                                              bias, gamma, beta, out, N);
}

// Round 20
// 143.615 us; speedup vs baseline: 1.1120x; 1.1120x over previous
//
#include <hip/hip_runtime.h>
#include <hip/hip_bf16.h>
#include <math.h>

#define IN_DIM 128
#define OUT_DIM 128
#define NHEAD 4
#define HC 32
#define NEG_SLOPE 0.2f
#define LN_EPS 1e-5f
#define SM_EPS 1e-16f

#define NB_SHIFT 9
#define BDST 512            // 1 << NB_SHIFT
#define NBUCK_MAX 256
#define BIN_ITER 28
#define BIN_CHUNK (BIN_ITER * 256)
#define SRC_BITS 17         // N < 131072
#define SRC_MASK ((1u << SRC_BITS) - 1u)
#define BCAP_SHIFT 14
#define BCAP (1 << BCAP_SHIFT)

typedef __attribute__((ext_vector_type(8))) short bf16x8;
typedef __attribute__((ext_vector_type(4))) short short4v;
typedef __attribute__((ext_vector_type(4))) float f32x4;

__device__ __forceinline__ float leaky(float v) { return v > 0.f ? v : NEG_SLOPE * v; }

__device__ __forceinline__ short f2b(float f) {
    __hip_bfloat16 b = __float2bfloat16(f);
    return *reinterpret_cast<short*>(&b);
}
__device__ __forceinline__ float b2f(short s) {
    return __uint_as_float(((unsigned)(unsigned short)s) << 16);
}

// byte offset into a tile of 256-byte rows, XOR row-swizzled (G4 fix)
__device__ __forceinline__ int swz(int row, int byteInRow) {
    return row * 256 + (byteInRow ^ ((row & 7) << 4));
}

// ---------------- K1: fused { edge binning (first) | MFMA GEMM + alpha } ----------------
// gemm branch stages W fp32 -> bf16 transposed LDS IN-BLOCK (no prepW kernel, no WtB).
__global__ void __launch_bounds__(256)
k_gemm_bin(const float* __restrict__ x, const float* __restrict__ W,
           const float* __restrict__ a_src, const float* __restrict__ a_dst,
           __hip_bfloat16* __restrict__ hB, float* __restrict__ asrc_out,
           float* __restrict__ adst_out,
           const int* __restrict__ ei, int* __restrict__ bcur,
           unsigned* __restrict__ binned,
           int E, int N, int nblk_bin)
{
    __shared__ __align__(16) char lds[32768];   // gemm: Wt swizzled; repack reuses [0,16K)
    const int t = threadIdx.x;

    if ((int)blockIdx.x < nblk_bin) {
        // ================= bin branch (fixed-capacity segments) =================
        int* cnt = (int*)lds;
        int* gb  = (int*)(lds + 1024);
        int tot = E + N;
        int base = (int)blockIdx.x * BIN_CHUNK;

        cnt[t] = 0;
        __syncthreads();

        int rk[BIN_ITER], bk[BIN_ITER], dlo[BIN_ITER];
        #pragma unroll
        for (int k = 0; k < BIN_ITER; ++k) {
            int e = base + k * 256 + t;
            bk[k] = -1; rk[k] = 0; dlo[k] = 0;
            if (e < tot) {
                int d = (e < E) ? ei[E + e] : (e - E);
                bk[k] = d >> NB_SHIFT;
                dlo[k] = d & (BDST - 1);
                rk[k] = atomicAdd(&cnt[bk[k]], 1);
            }
        }
        __syncthreads();
        gb[t] = cnt[t] ? ((t << BCAP_SHIFT) + atomicAdd(&bcur[t], cnt[t])) : 0;
        __syncthreads();
        #pragma unroll
        for (int k = 0; k < BIN_ITER; ++k) {
            int e = base + k * 256 + t;
            if (e < tot) {
                int s = (e < E) ? ei[e] : (e - E);
                binned[gb[bk[k]] + rk[k]] = (unsigned)s | ((unsigned)dlo[k] << SRC_BITS);
            }
        }
    } else {
        // ================= GEMM + alpha branch =================
        const int node0 = ((int)blockIdx.x - nblk_bin) * 64;

        // stage Wt from W fp32: task = (j, k-quad); 4 coalesced dword loads + 1 8B LDS write
        #pragma unroll
        for (int i = 0; i < 16; ++i) {
            int task = i * 256 + t;
            int j = task & 127;
            int k0 = (task >> 7) * 4;
            float w0 = W[(k0 + 0) * OUT_DIM + j];
            float w1 = W[(k0 + 1) * OUT_DIM + j];
            float w2 = W[(k0 + 2) * OUT_DIM + j];
            float w3 = W[(k0 + 3) * OUT_DIM + j];
            short4v wb = { f2b(w0), f2b(w1), f2b(w2), f2b(w3) };
            *reinterpret_cast<short4v*>(lds + swz(j, 2 * k0)) = wb;
        }

        const int wave = t >> 6, l = t & 63;
        const int lr = l & 15, lg = l >> 4;

        // A-fragments direct from x
        int arow = node0 + wave * 16 + lr;
        bf16x8 afrag[4];
        if (arow < N) {
            const float* xr = x + (size_t)arow * IN_DIM + lg * 8;
            #pragma unroll
            for (int kk = 0; kk < 4; ++kk) {
                float4 xa = *reinterpret_cast<const float4*>(xr + kk * 32);
                float4 xc = *reinterpret_cast<const float4*>(xr + kk * 32 + 4);
                afrag[kk] = (bf16x8){ f2b(xa.x), f2b(xa.y), f2b(xa.z), f2b(xa.w),
                                      f2b(xc.x), f2b(xc.y), f2b(xc.z), f2b(xc.w) };
            }
        } else {
            #pragma unroll
            for (int kk = 0; kk < 4; ++kk)
                afrag[kk] = (bf16x8){0,0,0,0,0,0,0,0};
        }

        __syncthreads();   // Wt staged

        f32x4 acc[8];
        #pragma unroll
        for (int cg = 0; cg < 8; ++cg) acc[cg] = (f32x4){0.f, 0.f, 0.f, 0.f};

        #pragma unroll
        for (int cg = 0; cg < 8; ++cg) {
            #pragma unroll
            for (int kk = 0; kk < 4; ++kk) {
                bf16x8 b = *reinterpret_cast<bf16x8*>(lds + swz(cg * 16 + lr, kk * 64 + lg * 16));
                acc[cg] = __builtin_amdgcn_mfma_f32_16x16x32_bf16(afrag[kk], b, acc[cg], 0, 0, 0);
            }
        }

        // repack D-fragments into bf16 out-tile in LDS (Wt dead now)
        __syncthreads();
        #pragma unroll
        for (int q = 0; q < 4; ++q) {
            int row = wave * 16 + lg * 4 + q;
            #pragma unroll
            for (int cg = 0; cg < 8; ++cg)
                *reinterpret_cast<short*>(lds + swz(row, (cg * 16 + lr) * 2)) = f2b(acc[cg][q]);
        }
        __syncthreads();

        // wide coalesced store + fused alpha: thread t -> row t>>2, head t&3
        {
            int row = t >> 2;
            int node = node0 + row;
            int head = t & 3;
            if (node < N) {
                char* dst = (char*)(hB + (size_t)node * OUT_DIM);
                const float4* asv = (const float4*)(a_src + head * HC);
                const float4* adv = (const float4*)(a_dst + head * HC);
                float s = 0.f, dd = 0.f;
                #pragma unroll
                for (int c = 0; c < 4; ++c) {
                    int bir = head * 64 + c * 16;
                    bf16x8 vv = *reinterpret_cast<bf16x8*>(lds + swz(row, bir));
                    *reinterpret_cast<bf16x8*>(dst + bir) = vv;
                    float4 a0 = asv[c * 2], a1 = asv[c * 2 + 1];
                    float4 d0 = adv[c * 2], d1 = adv[c * 2 + 1];
                    s  = fmaf(b2f(vv[0]), a0.x, s);  dd = fmaf(b2f(vv[0]), d0.x, dd);
                    s  = fmaf(b2f(vv[1]), a0.y, s);  dd = fmaf(b2f(vv[1]), d0.y, dd);
                    s  = fmaf(b2f(vv[2]), a0.z, s);  dd = fmaf(b2f(vv[2]), d0.z, dd);
                    s  = fmaf(b2f(vv[3]), a0.w, s);  dd = fmaf(b2f(vv[3]), d0.w, dd);
                    s  = fmaf(b2f(vv[4]), a1.x, s);  dd = fmaf(b2f(vv[4]), d1.x, dd);
                    s  = fmaf(b2f(vv[5]), a1.y, s);  dd = fmaf(b2f(vv[5]), d1.y, dd);
                    s  = fmaf(b2f(vv[6]), a1.z, s);  dd = fmaf(b2f(vv[6]), d1.z, dd);
                    s  = fmaf(b2f(vv[7]), a1.w, s);  dd = fmaf(b2f(vv[7]), d1.w, dd);
                }
                asrc_out[node * NHEAD + head] = s;
                adst_out[node * NHEAD + head] = dd;
            }
        }
    }
}

// ---------------- K3: per-bucket local CSR (512 threads, 1 thread/dst) ----------------
__global__ void __launch_bounds__(512)
k_bucket_csr(const unsigned* __restrict__ binned, const int* __restrict__ bcur,
             int* __restrict__ rowbeg, int* __restrict__ rowend,
             int* __restrict__ csr_src, int N)
{
    __shared__ int cnt[BDST];
    __shared__ int s2[BDST];
    int b = blockIdx.x;
    int t = threadIdx.x;
    int d0 = b << NB_SHIFT;
    int base = b << BCAP_SHIFT;
    int ne = bcur[b];

    cnt[t] = 0;
    __syncthreads();
    for (int i = t; i < ne; i += 512) {
        unsigned p = binned[base + i];
        atomicAdd(&cnt[p >> SRC_BITS], 1);
    }
    __syncthreads();
    int v = cnt[t];
    s2[t] = v;
    __syncthreads();
    #pragma unroll
    for (int off = 1; off < BDST; off <<= 1) {
        int tmp = (t >= off) ? s2[t - off] : 0;
        __syncthreads();
        s2[t] += tmp;
        __syncthreads();
    }
    int e0 = s2[t] - v;
    cnt[t] = e0;                      // reuse as write cursor
    if (d0 + t < N) {
        rowbeg[d0 + t] = base + e0;
        rowend[d0 + t] = base + e0 + v;
    }
    __syncthreads();
    for (int i = t; i < ne; i += 512) {
        unsigned p = binned[base + i];
        int r = atomicAdd(&cnt[p >> SRC_BITS], 1);
        csr_src[base + r] = (int)(p & SRC_MASK);
    }
}

// ---------------- K4: gather + softmax + aggregate + bias + LN + ReLU ----------------
// Exact R14 structure (best measured: 78.8 us).
__global__ void k_gather(const int* __restrict__ csr_src,
                         const int* __restrict__ rowbeg, const int* __restrict__ rowend,
                         const __hip_bfloat16* __restrict__ hB,
                         const float* __restrict__ asrc, const float* __restrict__ adst,
                         const float* __restrict__ bias, const float* __restrict__ gamma,
                         const float* __restrict__ beta, float* __restrict__ out, int N)
{
    int wave = threadIdx.x >> 6;
    int l = threadIdx.x & 63;
    int d = blockIdx.x * 4 + wave;
    if (d >= N) return;
    int head = l >> 4;
    const char* hp = (const char*)hB;
    unsigned voff = (unsigned)(l << 2);
    float ad = adst[d * NHEAD + head];
    int beg = __builtin_amdgcn_readfirstlane(rowbeg[d]);
    int end = __builtin_amdgcn_readfirstlane(rowend[d]);

    float ax0 = 0.f, ay0 = 0.f, dn0 = 0.f;
    float ax1 = 0.f, ay1 = 0.f, dn1 = 0.f;

    int idx = beg + (l & 15);
    int cl = idx < end ? idx : end - 1;
    int smine = csr_src[cl];
    float v = (idx < end) ? asrc[(unsigned)smine * NHEAD + head] : -1e30f;

    for (int c = beg; c < end; c += 16) {
        float ee = __expf(leaky(v + ad));        // padding -> exp(-2e29) = 0
        int scur = smine;
        int c2 = c + 16;
        if (c2 < end) {
            int idx2 = c2 + (l & 15);
            int cl2 = idx2 < end ? idx2 : end - 1;
            smine = csr_src[cl2];
            v = (idx2 < end) ? asrc[(unsigned)smine * NHEAD + head] : -1e30f;
        }

#define GLOAD(E_)                                                                     \
        unsigned se##E_ = (unsigned)__builtin_amdgcn_readlane(scur, (E_));            \
        unsigned hv##E_ = *(const unsigned*)(hp + ((se##E_ << 8) + voff));
#define GCONS(E_, AX_, AY_, DN_) {                                                    \
        float eb = __int_as_float(__builtin_amdgcn_ds_swizzle(                        \
            __float_as_int(ee), 0x10 | ((E_) << 5)));                                 \
        AX_ = fmaf(eb, __uint_as_float(hv##E_ << 16), AX_);                           \
        AY_ = fmaf(eb, __uint_as_float(hv##E_ & 0xffff0000u), AY_);  DN_ += eb;       \
    }
        { GLOAD(0) GLOAD(1) GLOAD(2) GLOAD(3) GLOAD(4) GLOAD(5) GLOAD(6) GLOAD(7)
          GCONS(0, ax0, ay0, dn0) GCONS(1, ax1, ay1, dn1)
          GCONS(2, ax0, ay0, dn0) GCONS(3, ax1, ay1, dn1)
          GCONS(4, ax0, ay0, dn0) GCONS(5, ax1, ay1, dn1)
          GCONS(6, ax0, ay0, dn0) GCONS(7, ax1, ay1, dn1) }
        { GLOAD(8) GLOAD(9) GLOAD(10) GLOAD(11) GLOAD(12) GLOAD(13) GLOAD(14) GLOAD(15)
          GCONS(8, ax0, ay0, dn0)  GCONS(9, ax1, ay1, dn1)
          GCONS(10, ax0, ay0, dn0) GCONS(11, ax1, ay1, dn1)
          GCONS(12, ax0, ay0, dn0) GCONS(13, ax1, ay1, dn1)
          GCONS(14, ax0, ay0, dn0) GCONS(15, ax1, ay1, dn1) }
#undef GLOAD
#undef GCONS
    }

    float accx = ax0 + ax1, accy = ay0 + ay1, den = dn0 + dn1;
    float inv = 1.f / (den + SM_EPS);
    float vx = accx * inv + bias[2 * l];
    float vy = accy * inv + bias[2 * l + 1];

    float s1 = vx + vy;
    float s2 = vx * vx + vy * vy;
    #pragma unroll
    for (int m = 32; m >= 1; m >>= 1) {
        s1 += __shfl_xor(s1, m, 64);
        s2 += __shfl_xor(s2, m, 64);
    }
    float mean = s1 * (1.f / OUT_DIM);
    float var = s2 * (1.f / OUT_DIM) - mean * mean;
    float r = rsqrtf(var + LN_EPS);
    float ox = (vx - mean) * r * gamma[2 * l] + beta[2 * l];
    float oy = (vy - mean) * r * gamma[2 * l + 1] + beta[2 * l + 1];
    ox = ox > 0.f ? ox : 0.f;
    oy = oy > 0.f ? oy : 0.f;
    *reinterpret_cast<float2*>(&out[(size_t)d * OUT_DIM + 2 * l]) = make_float2(ox, oy);
}

extern "C" void kernel_launch(void* const* d_in, const int* in_sizes, int n_in,
                              void* d_out, int out_size, void* d_ws, size_t ws_size,
                              hipStream_t stream) {
    const float* x      = (const float*)d_in[0];
    const int*   ei     = (const int*)d_in[1];
    const float* W      = (const float*)d_in[2];
    const float* a_src  = (const float*)d_in[3];
    const float* a_dst  = (const float*)d_in[4];
    const float* bias   = (const float*)d_in[5];
    const float* gamma  = (const float*)d_in[6];
    const float* beta   = (const float*)d_in[7];
    float* out = (float*)d_out;

    const int N = in_sizes[0] / IN_DIM;
    const int E = in_sizes[1] / 2;
    const int TOT = E + N;
    const int nbuck = (N + BDST - 1) >> NB_SHIFT;
    const int nblk_gemm = (N + 63) / 64;
    const int nblk_bin = (TOT + BIN_CHUNK - 1) / BIN_CHUNK;

    // workspace layout
    char* p = (char*)d_ws;
    __hip_bfloat16* hB = (__hip_bfloat16*)p;  p += (size_t)N * OUT_DIM * sizeof(__hip_bfloat16);
    float* asrc   = (float*)p;                p += (size_t)N * NHEAD * sizeof(float);
    float* adst   = (float*)p;                p += (size_t)N * NHEAD * sizeof(float);
    int* bcur     = (int*)p;                  p += NBUCK_MAX * sizeof(int);
    int* rowbeg   = (int*)p;                  p += (size_t)N * sizeof(int);
    int* rowend   = (int*)p;                  p += (size_t)N * sizeof(int);
    unsigned* binned = (unsigned*)p;          p += (size_t)nbuck * BCAP * sizeof(unsigned);
    int* csr_src  = (int*)p;                  p += (size_t)nbuck * BCAP * sizeof(int);

    (void)hipMemsetAsync(bcur, 0, NBUCK_MAX * sizeof(int), stream);

    k_gemm_bin<<<nblk_bin + nblk_gemm, 256, 0, stream>>>(x, W, a_src, a_dst, hB, asrc, adst,
                                                         ei, bcur, binned, E, N, nblk_bin);
    k_bucket_csr<<<nbuck, 512, 0, stream>>>(binned, bcur, rowbeg, rowend, csr_src, N);
    k_gather<<<(N + 3) / 4, 256, 0, stream>>>(csr_src, rowbeg, rowend, hB, asrc, adst,
                                              bias, gamma, beta, out, N);
}